// Round 1
// baseline (2932.602 us; speedup 1.0000x reference)
//
#include <hip/hip_runtime.h>
#include <hip/hip_bf16.h>
#include <stdint.h>

#define M_NODES 100000
#define NE      300000
#define D       256
#define D2      512
#define NLAYERS 4

typedef float  f32x4  __attribute__((ext_vector_type(4)));
typedef __bf16 bf16x8 __attribute__((ext_vector_type(8)));

static __device__ __forceinline__ float bf2f(uint32_t u) {
  union { uint32_t i; float f; } v; v.i = u << 16; return v.f;
}
static __device__ __forceinline__ uint32_t f2bf(float f) {
  union { float f; uint32_t i; } v; v.f = f;
  return (v.i + 0x7fffu + ((v.i >> 16) & 1u)) >> 16;
}
static __device__ __forceinline__ void gload_lds16(const void* g, void* l) {
  __builtin_amdgcn_global_load_lds((const __attribute__((address_space(1))) uint32_t*)g,
                                   (__attribute__((address_space(3))) uint32_t*)l, 16, 0, 0);
}

// ---------------- CSR build ----------------
__global__ void hist_kernel(const int* __restrict__ rows, int* __restrict__ counts) {
  int e = blockIdx.x * 256 + threadIdx.x;
  if (e < NE) atomicAdd(&counts[rows[e]], 1);
}

__global__ void scan1_kernel(const int* __restrict__ counts, int* __restrict__ rp,
                             int* __restrict__ bsum) {
  __shared__ int sd[256];
  int tid = threadIdx.x;
  int base = blockIdx.x * 1024 + tid * 4;
  int v0 = (base + 0 < M_NODES) ? counts[base + 0] : 0;
  int v1 = (base + 1 < M_NODES) ? counts[base + 1] : 0;
  int v2 = (base + 2 < M_NODES) ? counts[base + 2] : 0;
  int v3 = (base + 3 < M_NODES) ? counts[base + 3] : 0;
  int tsum = v0 + v1 + v2 + v3;
  sd[tid] = tsum; __syncthreads();
  for (int off = 1; off < 256; off <<= 1) {
    int x = sd[tid];
    if (tid >= off) x += sd[tid - off];
    __syncthreads(); sd[tid] = x; __syncthreads();
  }
  int excl = sd[tid] - tsum;
  if (base + 0 < M_NODES) rp[base + 0] = excl; excl += v0;
  if (base + 1 < M_NODES) rp[base + 1] = excl; excl += v1;
  if (base + 2 < M_NODES) rp[base + 2] = excl; excl += v2;
  if (base + 3 < M_NODES) rp[base + 3] = excl;
  if (tid == 255) bsum[blockIdx.x] = sd[255];
}

__global__ void scan2_kernel(const int* __restrict__ bsum, int* __restrict__ boff) {
  __shared__ int sd[128];
  int tid = threadIdx.x;
  int v = (tid < 98) ? bsum[tid] : 0;
  sd[tid] = v; __syncthreads();
  for (int off = 1; off < 128; off <<= 1) {
    int x = sd[tid];
    if (tid >= off) x += sd[tid - off];
    __syncthreads(); sd[tid] = x; __syncthreads();
  }
  if (tid < 98) boff[tid] = sd[tid] - v;
}

__global__ void scan3_kernel(int* __restrict__ rp, const int* __restrict__ boff,
                             int* __restrict__ cursor) {
  int i = blockIdx.x * 256 + threadIdx.x;
  if (i > M_NODES) return;
  int v = (i < M_NODES) ? rp[i] + boff[i >> 10] : NE;
  rp[i] = v;
  if (i < M_NODES) cursor[i] = v;
}

__global__ void scatter_kernel(const int* __restrict__ rows, const int* __restrict__ cols,
                               const float* __restrict__ vals, int* __restrict__ cursor,
                               int* __restrict__ e_col, float* __restrict__ e_val) {
  int e = blockIdx.x * 256 + threadIdx.x;
  if (e >= NE) return;
  int r = rows[e];
  int p = atomicAdd(&cursor[r], 1);
  e_col[p] = cols[e];
  e_val[p] = vals[e];
}

// ---------------- conversions ----------------
__global__ void conv_x_kernel(const float* __restrict__ x, ushort* __restrict__ h) {
  size_t idx = (size_t)blockIdx.x * 256 + threadIdx.x;  // M*D/4 threads
  size_t i = idx >> 6; int c = (int)(idx & 63) * 4;
  float4 v = *(const float4*)(x + i * D + c);
  ushort4 o;
  o.x = (ushort)f2bf(v.x); o.y = (ushort)f2bf(v.y);
  o.z = (ushort)f2bf(v.z); o.w = (ushort)f2bf(v.w);
  *(ushort4*)(h + i * D + c) = o;
}

__global__ void copy_x_kernel(const float* __restrict__ x, float* __restrict__ out) {
  size_t idx = (size_t)blockIdx.x * 256 + threadIdx.x;  // M*D/4 threads
  size_t i = idx >> 6; int c = (int)(idx & 63) * 4;
  float4 v = *(const float4*)(x + i * D + c);
  *(float4*)(out + i * D2 + D + c) = v;
}

// Bt[layer][n][k] = bf16( n<256 ? W[layer][k][n] : SW[layer][k][n-256] )
__global__ void conv_w_kernel(const float* __restrict__ W, const float* __restrict__ SW,
                              ushort* __restrict__ Bt) {
  int idx = blockIdx.x * 256 + threadIdx.x;  // 4*512*256 = 524288
  if (idx >= NLAYERS * D2 * D) return;
  int k = idx & (D - 1);
  int n = (idx >> 8) & (D2 - 1);
  int layer = idx >> 17;
  float v = (n < D) ? W[(size_t)layer * D * D + k * D + n]
                    : SW[(size_t)layer * D * D + k * D + (n - D)];
  Bt[idx] = (ushort)f2bf(v);
}

// ---------------- GEMM: [M,256](bf16) x [256,512](bf16, N-major) -> AB [M,512](bf16) ----------------
#define BM 128
#define BN 128
#define BK 64

__global__ __launch_bounds__(256, 2)
void gemm_kernel(const ushort* __restrict__ h, const ushort* __restrict__ Bt,
                 ushort* __restrict__ outAB) {
  __shared__ __align__(16) ushort As[BM * BK];  // [128][64], row = 128B
  __shared__ __align__(16) ushort Bs[BN * BK];  // [128 n][64 k]
  const int tid = threadIdx.x;
  const int m0 = blockIdx.x * BM;
  const int n0 = blockIdx.y * BN;
  const int wv = tid >> 6, l = tid & 63;
  const int wr = wv >> 1, wc = wv & 1;
  const int lrow = l & 15, lhi = l >> 4;

  f32x4 acc[4][4] = {};

  const int arow = tid >> 3;          // 0..31
  const int acb  = (tid & 7) << 4;    // byte col 0..112

#pragma unroll
  for (int s = 0; s < 4; ++s) {
    const int k0 = s * BK;
    // stage A
#pragma unroll
    for (int p = 0; p < 4; ++p) {
      int row = p * 32 + arow;
      int grow = m0 + row; if (grow >= M_NODES) grow = M_NODES - 1;
      int gcb = acb ^ ((row & 7) << 4);
      gload_lds16(h + (size_t)grow * D + k0 + (gcb >> 1), As + row * BK + (acb >> 1));
    }
    // stage B (Bt is [512][256], n-major)
#pragma unroll
    for (int p = 0; p < 4; ++p) {
      int row = p * 32 + arow;
      int gn = n0 + row;
      int gcb = acb ^ ((row & 7) << 4);
      gload_lds16(Bt + (size_t)gn * D + k0 + (gcb >> 1), Bs + row * BK + (acb >> 1));
    }
    __syncthreads();
#pragma unroll
    for (int kk = 0; kk < 2; ++kk) {
      bf16x8 af[4], bfr[4];
#pragma unroll
      for (int mi = 0; mi < 4; ++mi) {
        int row = wr * 64 + mi * 16 + lrow;
        int off = row * 128 + ((kk * 64 + lhi * 16) ^ ((row & 7) << 4));
        af[mi] = *(const bf16x8*)((const char*)As + off);
      }
#pragma unroll
      for (int nj = 0; nj < 4; ++nj) {
        int row = wc * 64 + nj * 16 + lrow;
        int off = row * 128 + ((kk * 64 + lhi * 16) ^ ((row & 7) << 4));
        bfr[nj] = *(const bf16x8*)((const char*)Bs + off);
      }
#pragma unroll
      for (int mi = 0; mi < 4; ++mi)
#pragma unroll
        for (int nj = 0; nj < 4; ++nj)
          acc[mi][nj] = __builtin_amdgcn_mfma_f32_16x16x32_bf16(af[mi], bfr[nj], acc[mi][nj], 0, 0, 0);
    }
    __syncthreads();
  }

  // epilogue: C/D map col=lane&15, row=(lane>>4)*4+reg
#pragma unroll
  for (int mi = 0; mi < 4; ++mi) {
#pragma unroll
    for (int nj = 0; nj < 4; ++nj) {
      int gc = n0 + wc * 64 + nj * 16 + lrow;
#pragma unroll
      for (int r = 0; r < 4; ++r) {
        int grow = m0 + wr * 64 + mi * 16 + lhi * 4 + r;
        if (grow < M_NODES)
          outAB[(size_t)grow * D2 + gc] = (ushort)f2bf(acc[mi][nj][r]);
      }
    }
  }
}

// ---------------- SpMM + selfterm + BN stats ----------------
// AB: [M][512] bf16; cols 0..255 = support, cols 256..511 = selfterm (overwritten with pre-BN out)
__global__ __launch_bounds__(256, 4)
void spmm_kernel(ushort* __restrict__ AB, const int* __restrict__ rp,
                 const int* __restrict__ e_col, const float* __restrict__ e_val,
                 float* __restrict__ stats) {
  const int wv = threadIdx.x >> 6, l = threadIdx.x & 63;
  float s0 = 0, s1 = 0, s2 = 0, s3 = 0, q0 = 0, q1 = 0, q2 = 0, q3 = 0;
  for (int t = 0; t < 16; ++t) {
    int i = blockIdx.x * 64 + t * 4 + wv;
    if (i >= M_NODES) break;
    const ushort4 st = *(const ushort4*)(AB + (size_t)i * D2 + D + 4 * l);
    float a0 = bf2f(st.x), a1 = bf2f(st.y), a2 = bf2f(st.z), a3 = bf2f(st.w);
    int e0 = rp[i], e1 = rp[i + 1];
    for (int e = e0; e < e1; ++e) {
      float v = e_val[e];
      int c = e_col[e];
      const ushort4 sp = *(const ushort4*)(AB + (size_t)c * D2 + 4 * l);
      a0 += v * bf2f(sp.x); a1 += v * bf2f(sp.y);
      a2 += v * bf2f(sp.z); a3 += v * bf2f(sp.w);
    }
    ushort4 o;
    o.x = (ushort)f2bf(a0); o.y = (ushort)f2bf(a1);
    o.z = (ushort)f2bf(a2); o.w = (ushort)f2bf(a3);
    *(ushort4*)(AB + (size_t)i * D2 + D + 4 * l) = o;
    s0 += a0; q0 += a0 * a0; s1 += a1; q1 += a1 * a1;
    s2 += a2; q2 += a2 * a2; s3 += a3; q3 += a3 * a3;
  }
  int c0 = 4 * l;
  atomicAdd(&stats[c0 + 0], s0); atomicAdd(&stats[c0 + 1], s1);
  atomicAdd(&stats[c0 + 2], s2); atomicAdd(&stats[c0 + 3], s3);
  atomicAdd(&stats[D + c0 + 0], q0); atomicAdd(&stats[D + c0 + 1], q1);
  atomicAdd(&stats[D + c0 + 2], q2); atomicAdd(&stats[D + c0 + 3], q3);
}

__global__ void bn_fin_kernel(const float* __restrict__ stats, const float* __restrict__ gamma,
                              const float* __restrict__ beta, float* __restrict__ scale,
                              float* __restrict__ shift) {
  int c = threadIdx.x;
  float mean = stats[c] * (1.0f / M_NODES);
  float var = stats[D + c] * (1.0f / M_NODES) - mean * mean;
  float rstd = rsqrtf(var + 1e-5f);
  float sc = gamma[c] * rstd;
  scale[c] = sc;
  shift[c] = beta[c] - mean * sc;
}

__global__ void norm_bf16_kernel(const ushort* __restrict__ AB, const float* __restrict__ scale,
                                 const float* __restrict__ shift, ushort* __restrict__ hout) {
  size_t idx = (size_t)blockIdx.x * 256 + threadIdx.x;  // M*D/8
  if (idx >= (size_t)M_NODES * D / 8) return;
  size_t i = idx >> 5; int c = (int)(idx & 31) * 8;
  uint4 u = *(const uint4*)(AB + i * D2 + D + c);
  float4 sc0 = *(const float4*)(scale + c), sc1 = *(const float4*)(scale + c + 4);
  float4 sh0 = *(const float4*)(shift + c), sh1 = *(const float4*)(shift + c + 4);
  float f0 = fmaxf(bf2f(u.x & 0xffff) * sc0.x + sh0.x, 0.f);
  float f1 = fmaxf(bf2f(u.x >> 16)    * sc0.y + sh0.y, 0.f);
  float f2 = fmaxf(bf2f(u.y & 0xffff) * sc0.z + sh0.z, 0.f);
  float f3 = fmaxf(bf2f(u.y >> 16)    * sc0.w + sh0.w, 0.f);
  float f4 = fmaxf(bf2f(u.z & 0xffff) * sc1.x + sh1.x, 0.f);
  float f5 = fmaxf(bf2f(u.z >> 16)    * sc1.y + sh1.y, 0.f);
  float f6 = fmaxf(bf2f(u.w & 0xffff) * sc1.z + sh1.z, 0.f);
  float f7 = fmaxf(bf2f(u.w >> 16)    * sc1.w + sh1.w, 0.f);
  uint4 o;
  o.x = f2bf(f0) | (f2bf(f1) << 16);
  o.y = f2bf(f2) | (f2bf(f3) << 16);
  o.z = f2bf(f4) | (f2bf(f5) << 16);
  o.w = f2bf(f6) | (f2bf(f7) << 16);
  *(uint4*)(hout + i * D + c) = o;
}

__global__ void norm_f32_out_kernel(const ushort* __restrict__ AB, const float* __restrict__ scale,
                                    const float* __restrict__ shift, float* __restrict__ out) {
  size_t idx = (size_t)blockIdx.x * 256 + threadIdx.x;  // M*D/8
  if (idx >= (size_t)M_NODES * D / 8) return;
  size_t i = idx >> 5; int c = (int)(idx & 31) * 8;
  uint4 u = *(const uint4*)(AB + i * D2 + D + c);
  float4 sc0 = *(const float4*)(scale + c), sc1 = *(const float4*)(scale + c + 4);
  float4 sh0 = *(const float4*)(shift + c), sh1 = *(const float4*)(shift + c + 4);
  float4 r0, r1;
  r0.x = fmaxf(bf2f(u.x & 0xffff) * sc0.x + sh0.x, 0.f);
  r0.y = fmaxf(bf2f(u.x >> 16)    * sc0.y + sh0.y, 0.f);
  r0.z = fmaxf(bf2f(u.y & 0xffff) * sc0.z + sh0.z, 0.f);
  r0.w = fmaxf(bf2f(u.y >> 16)    * sc0.w + sh0.w, 0.f);
  r1.x = fmaxf(bf2f(u.z & 0xffff) * sc1.x + sh1.x, 0.f);
  r1.y = fmaxf(bf2f(u.z >> 16)    * sc1.y + sh1.y, 0.f);
  r1.z = fmaxf(bf2f(u.w & 0xffff) * sc1.z + sh1.z, 0.f);
  r1.w = fmaxf(bf2f(u.w >> 16)    * sc1.w + sh1.w, 0.f);
  *(float4*)(out + i * D2 + c) = r0;
  *(float4*)(out + i * D2 + c + 4) = r1;
}

// ---------------- launch ----------------
extern "C" void kernel_launch(void* const* d_in, const int* in_sizes, int n_in,
                              void* d_out, int out_size, void* d_ws, size_t ws_size,
                              hipStream_t stream) {
  const float* x      = (const float*)d_in[0];
  const float* vals   = (const float*)d_in[1];
  const float* W      = (const float*)d_in[2];
  const float* SW     = (const float*)d_in[3];
  const float* gammas = (const float*)d_in[4];
  const float* betas  = (const float*)d_in[5];
  const int*   rows   = (const int*)d_in[6];
  const int*   cols   = (const int*)d_in[7];
  float* out = (float*)d_out;

  char* ws = (char*)d_ws;
  size_t off = 0;
  auto alloc = [&](size_t bytes) {
    void* p = ws + off;
    off = (off + bytes + 255) & ~(size_t)255;
    return p;
  };
  ushort* h    = (ushort*)alloc((size_t)M_NODES * D * 2);
  ushort* AB   = (ushort*)alloc((size_t)M_NODES * D2 * 2);
  ushort* Bt   = (ushort*)alloc((size_t)NLAYERS * D2 * D * 2);
  int*   rp    = (int*)alloc((M_NODES + 1) * 4);
  int*   cursor= (int*)alloc((M_NODES + 1) * 4);
  int*   e_col = (int*)alloc(NE * 4);
  float* e_val = (float*)alloc(NE * 4);
  int*   bsum  = (int*)alloc(512);
  int*   boff  = (int*)alloc(512);
  float* stats = (float*)alloc(NLAYERS * 2 * D * 4);
  float* scale = (float*)alloc(D * 4);
  float* shift = (float*)alloc(D * 4);

  hipMemsetAsync(cursor, 0, (size_t)M_NODES * 4, stream);  // counts
  hipMemsetAsync(stats, 0, (size_t)NLAYERS * 2 * D * 4, stream);

  hist_kernel<<<(NE + 255) / 256, 256, 0, stream>>>(rows, cursor);
  scan1_kernel<<<98, 256, 0, stream>>>(cursor, rp, bsum);
  scan2_kernel<<<1, 128, 0, stream>>>(bsum, boff);
  scan3_kernel<<<(M_NODES + 256) / 256, 256, 0, stream>>>(rp, boff, cursor);
  scatter_kernel<<<(NE + 255) / 256, 256, 0, stream>>>(rows, cols, vals, cursor, e_col, e_val);

  conv_x_kernel<<<(M_NODES * D / 4) / 256, 256, 0, stream>>>(x, h);
  conv_w_kernel<<<(NLAYERS * D2 * D) / 256, 256, 0, stream>>>(W, SW, Bt);
  copy_x_kernel<<<(M_NODES * D / 4) / 256, 256, 0, stream>>>(x, out);

  for (int lyr = 0; lyr < NLAYERS; ++lyr) {
    gemm_kernel<<<dim3((M_NODES + BM - 1) / BM, D2 / BN), 256, 0, stream>>>(
        h, Bt + (size_t)lyr * D2 * D, AB);
    spmm_kernel<<<(M_NODES + 63) / 64, 256, 0, stream>>>(AB, rp, e_col, e_val,
                                                         stats + (size_t)lyr * 2 * D);
    bn_fin_kernel<<<1, 256, 0, stream>>>(stats + (size_t)lyr * 2 * D, gammas + lyr * D,
                                         betas + lyr * D, scale, shift);
    if (lyr < NLAYERS - 1)
      norm_bf16_kernel<<<(M_NODES * D / 8) / 256 + 1, 256, 0, stream>>>(AB, scale, shift, h);
    else
      norm_f32_out_kernel<<<(M_NODES * D / 8) / 256 + 1, 256, 0, stream>>>(AB, scale, shift, out);
  }
}

// Round 2
// 708.623 us; speedup vs baseline: 4.1384x; 4.1384x over previous
//
#include <hip/hip_runtime.h>
#include <hip/hip_bf16.h>
#include <stdint.h>

#define M_NODES 100000
#define NE      300000
#define D       256
#define D2      512
#define NLAYERS 4

typedef float  f32x4  __attribute__((ext_vector_type(4)));
typedef __bf16 bf16x8 __attribute__((ext_vector_type(8)));

static __device__ __forceinline__ float bf2f(uint32_t u) {
  union { uint32_t i; float f; } v; v.i = u << 16; return v.f;
}
static __device__ __forceinline__ uint32_t f2bf(float f) {
  union { float f; uint32_t i; } v; v.f = f;
  return (v.i + 0x7fffu + ((v.i >> 16) & 1u)) >> 16;
}
static __device__ __forceinline__ void gload_lds16(const void* g, void* l) {
  __builtin_amdgcn_global_load_lds((const __attribute__((address_space(1))) uint32_t*)g,
                                   (__attribute__((address_space(3))) uint32_t*)l, 16, 0, 0);
}

// ---------------- CSR build ----------------
__global__ void hist_kernel(const int* __restrict__ rows, int* __restrict__ counts) {
  int e = blockIdx.x * 256 + threadIdx.x;
  if (e < NE) atomicAdd(&counts[rows[e]], 1);
}

__global__ void scan1_kernel(const int* __restrict__ counts, int* __restrict__ rp,
                             int* __restrict__ bsum) {
  __shared__ int sd[256];
  int tid = threadIdx.x;
  int base = blockIdx.x * 1024 + tid * 4;
  int v0 = (base + 0 < M_NODES) ? counts[base + 0] : 0;
  int v1 = (base + 1 < M_NODES) ? counts[base + 1] : 0;
  int v2 = (base + 2 < M_NODES) ? counts[base + 2] : 0;
  int v3 = (base + 3 < M_NODES) ? counts[base + 3] : 0;
  int tsum = v0 + v1 + v2 + v3;
  sd[tid] = tsum; __syncthreads();
  for (int off = 1; off < 256; off <<= 1) {
    int x = sd[tid];
    if (tid >= off) x += sd[tid - off];
    __syncthreads(); sd[tid] = x; __syncthreads();
  }
  int excl = sd[tid] - tsum;
  if (base + 0 < M_NODES) rp[base + 0] = excl; excl += v0;
  if (base + 1 < M_NODES) rp[base + 1] = excl; excl += v1;
  if (base + 2 < M_NODES) rp[base + 2] = excl; excl += v2;
  if (base + 3 < M_NODES) rp[base + 3] = excl;
  if (tid == 255) bsum[blockIdx.x] = sd[255];
}

__global__ void scan2_kernel(const int* __restrict__ bsum, int* __restrict__ boff) {
  __shared__ int sd[128];
  int tid = threadIdx.x;
  int v = (tid < 98) ? bsum[tid] : 0;
  sd[tid] = v; __syncthreads();
  for (int off = 1; off < 128; off <<= 1) {
    int x = sd[tid];
    if (tid >= off) x += sd[tid - off];
    __syncthreads(); sd[tid] = x; __syncthreads();
  }
  if (tid < 98) boff[tid] = sd[tid] - v;
}

__global__ void scan3_kernel(int* __restrict__ rp, const int* __restrict__ boff,
                             int* __restrict__ cursor) {
  int i = blockIdx.x * 256 + threadIdx.x;
  if (i > M_NODES) return;
  int v = (i < M_NODES) ? rp[i] + boff[i >> 10] : NE;
  rp[i] = v;
  if (i < M_NODES) cursor[i] = v;
}

__global__ void scatter_kernel(const int* __restrict__ rows, const int* __restrict__ cols,
                               const float* __restrict__ vals, int* __restrict__ cursor,
                               int* __restrict__ e_col, float* __restrict__ e_val) {
  int e = blockIdx.x * 256 + threadIdx.x;
  if (e >= NE) return;
  int r = rows[e];
  int p = atomicAdd(&cursor[r], 1);
  e_col[p] = cols[e];
  e_val[p] = vals[e];
}

// ---------------- conversions ----------------
__global__ void conv_x_kernel(const float* __restrict__ x, ushort* __restrict__ h) {
  size_t idx = (size_t)blockIdx.x * 256 + threadIdx.x;  // M*D/4 threads
  size_t i = idx >> 6; int c = (int)(idx & 63) * 4;
  float4 v = *(const float4*)(x + i * D + c);
  ushort4 o;
  o.x = (ushort)f2bf(v.x); o.y = (ushort)f2bf(v.y);
  o.z = (ushort)f2bf(v.z); o.w = (ushort)f2bf(v.w);
  *(ushort4*)(h + i * D + c) = o;
}

__global__ void copy_x_kernel(const float* __restrict__ x, float* __restrict__ out) {
  size_t idx = (size_t)blockIdx.x * 256 + threadIdx.x;  // M*D/4 threads
  size_t i = idx >> 6; int c = (int)(idx & 63) * 4;
  float4 v = *(const float4*)(x + i * D + c);
  *(float4*)(out + i * D2 + D + c) = v;
}

// Bt[layer][n][k] = bf16( n<256 ? W[layer][k][n] : SW[layer][k][n-256] )
__global__ void conv_w_kernel(const float* __restrict__ W, const float* __restrict__ SW,
                              ushort* __restrict__ Bt) {
  int idx = blockIdx.x * 256 + threadIdx.x;  // 4*512*256 = 524288
  if (idx >= NLAYERS * D2 * D) return;
  int k = idx & (D - 1);
  int n = (idx >> 8) & (D2 - 1);
  int layer = idx >> 17;
  float v = (n < D) ? W[(size_t)layer * D * D + k * D + n]
                    : SW[(size_t)layer * D * D + k * D + (n - D)];
  Bt[idx] = (ushort)f2bf(v);
}

// ---------------- GEMM: [M,256](bf16) x [256,512](bf16, N-major) -> AB [M,512](bf16) ----------------
#define BM 128
#define BN 128
#define BK 64

__global__ __launch_bounds__(256, 2)
void gemm_kernel(const ushort* __restrict__ h, const ushort* __restrict__ Bt,
                 ushort* __restrict__ outAB) {
  __shared__ __align__(16) ushort As[BM * BK];  // [128][64], row = 128B
  __shared__ __align__(16) ushort Bs[BN * BK];  // [128 n][64 k]
  const int tid = threadIdx.x;
  const int m0 = blockIdx.x * BM;
  const int n0 = blockIdx.y * BN;
  const int wv = tid >> 6, l = tid & 63;
  const int wr = wv >> 1, wc = wv & 1;
  const int lrow = l & 15, lhi = l >> 4;

  f32x4 acc[4][4] = {};

  const int arow = tid >> 3;          // 0..31
  const int acb  = (tid & 7) << 4;    // byte col 0..112

#pragma unroll
  for (int s = 0; s < 4; ++s) {
    const int k0 = s * BK;
    // stage A
#pragma unroll
    for (int p = 0; p < 4; ++p) {
      int row = p * 32 + arow;
      int grow = m0 + row; if (grow >= M_NODES) grow = M_NODES - 1;
      int gcb = acb ^ ((row & 7) << 4);
      gload_lds16(h + (size_t)grow * D + k0 + (gcb >> 1), As + row * BK + (acb >> 1));
    }
    // stage B (Bt is [512][256], n-major)
#pragma unroll
    for (int p = 0; p < 4; ++p) {
      int row = p * 32 + arow;
      int gn = n0 + row;
      int gcb = acb ^ ((row & 7) << 4);
      gload_lds16(Bt + (size_t)gn * D + k0 + (gcb >> 1), Bs + row * BK + (acb >> 1));
    }
    __syncthreads();
#pragma unroll
    for (int kk = 0; kk < 2; ++kk) {
      bf16x8 af[4], bfr[4];
#pragma unroll
      for (int mi = 0; mi < 4; ++mi) {
        int row = wr * 64 + mi * 16 + lrow;
        int off = row * 128 + ((kk * 64 + lhi * 16) ^ ((row & 7) << 4));
        af[mi] = *(const bf16x8*)((const char*)As + off);
      }
#pragma unroll
      for (int nj = 0; nj < 4; ++nj) {
        int row = wc * 64 + nj * 16 + lrow;
        int off = row * 128 + ((kk * 64 + lhi * 16) ^ ((row & 7) << 4));
        bfr[nj] = *(const bf16x8*)((const char*)Bs + off);
      }
#pragma unroll
      for (int mi = 0; mi < 4; ++mi)
#pragma unroll
        for (int nj = 0; nj < 4; ++nj)
          acc[mi][nj] = __builtin_amdgcn_mfma_f32_16x16x32_bf16(af[mi], bfr[nj], acc[mi][nj], 0, 0, 0);
    }
    __syncthreads();
  }

  // epilogue: C/D map col=lane&15, row=(lane>>4)*4+reg
#pragma unroll
  for (int mi = 0; mi < 4; ++mi) {
#pragma unroll
    for (int nj = 0; nj < 4; ++nj) {
      int gc = n0 + wc * 64 + nj * 16 + lrow;
#pragma unroll
      for (int r = 0; r < 4; ++r) {
        int grow = m0 + wr * 64 + mi * 16 + lhi * 4 + r;
        if (grow < M_NODES)
          outAB[(size_t)grow * D2 + gc] = (ushort)f2bf(acc[mi][nj][r]);
      }
    }
  }
}

// ---------------- SpMM + selfterm + BN stats (latency-optimized) ----------------
// AB: [M][512] bf16; cols 0..255 = support, cols 256..511 = selfterm (overwritten with pre-BN out)
// One wave owns a contiguous CHUNK of rows. rp for the chunk is preloaded
// lane-parallel; per-row edge metadata loaded lane-parallel in one shot;
// gathers issued in batches of 4 independent loads.
#define SPMM_CHUNK 16

__global__ __launch_bounds__(256, 4)
void spmm_kernel(ushort* __restrict__ AB, const int* __restrict__ rp,
                 const int* __restrict__ e_col, const float* __restrict__ e_val,
                 float* __restrict__ stats) {
  __shared__ float sstats[2 * D];
  for (int i = threadIdx.x; i < 2 * D; i += 256) sstats[i] = 0.f;
  __syncthreads();

  const int wv = threadIdx.x >> 6, l = threadIdx.x & 63;
  const int wave = blockIdx.x * 4 + wv;
  const int row0 = wave * SPMM_CHUNK;

  float s0 = 0, s1 = 0, s2 = 0, s3 = 0, q0 = 0, q1 = 0, q2 = 0, q3 = 0;

  if (row0 < M_NODES) {
    const int nrows = (M_NODES - row0 < SPMM_CHUNK) ? (M_NODES - row0) : SPMM_CHUNK;
    // lane-parallel rowptr preload for the chunk (lanes 0..nrows)
    int myrp = (l <= nrows) ? rp[row0 + l] : 0;

    for (int t = 0; t < nrows; ++t) {
      const int i = row0 + t;
      const int e0 = __shfl(myrp, t);
      const int e1 = __shfl(myrp, t + 1);
      const int deg = e1 - e0;

      const ushort4 st = *(const ushort4*)(AB + (size_t)i * D2 + D + 4 * l);
      float a0 = bf2f(st.x), a1 = bf2f(st.y), a2 = bf2f(st.z), a3 = bf2f(st.w);

      for (int b = 0; b < deg; b += 64) {
        const int nb = (deg - b < 64) ? (deg - b) : 64;
        // lane-parallel metadata load for this batch of edges
        int   myc = (l < nb) ? e_col[e0 + b + l] : 0;
        float myv = (l < nb) ? e_val[e0 + b + l] : 0.f;

        for (int e = 0; e < nb; e += 4) {
          int cc[4]; float vv[4]; ushort4 sp[4];
#pragma unroll
          for (int j = 0; j < 4; ++j) {
            int ee = (e + j < nb) ? (e + j) : (nb - 1);   // clamp (dup load harmless)
            cc[j] = __shfl(myc, ee);
            vv[j] = (e + j < nb) ? __shfl(myv, e + j) : 0.f;
            sp[j] = *(const ushort4*)(AB + (size_t)cc[j] * D2 + 4 * l);
          }
#pragma unroll
          for (int j = 0; j < 4; ++j) {
            a0 += vv[j] * bf2f(sp[j].x);
            a1 += vv[j] * bf2f(sp[j].y);
            a2 += vv[j] * bf2f(sp[j].z);
            a3 += vv[j] * bf2f(sp[j].w);
          }
        }
      }

      ushort4 o;
      o.x = (ushort)f2bf(a0); o.y = (ushort)f2bf(a1);
      o.z = (ushort)f2bf(a2); o.w = (ushort)f2bf(a3);
      *(ushort4*)(AB + (size_t)i * D2 + D + 4 * l) = o;
      s0 += a0; q0 += a0 * a0; s1 += a1; q1 += a1 * a1;
      s2 += a2; q2 += a2 * a2; s3 += a3; q3 += a3 * a3;
    }
  }

  // block-level LDS reduction, then one global atomic per address per block
  const int c0 = 4 * l;
  atomicAdd(&sstats[c0 + 0], s0); atomicAdd(&sstats[c0 + 1], s1);
  atomicAdd(&sstats[c0 + 2], s2); atomicAdd(&sstats[c0 + 3], s3);
  atomicAdd(&sstats[D + c0 + 0], q0); atomicAdd(&sstats[D + c0 + 1], q1);
  atomicAdd(&sstats[D + c0 + 2], q2); atomicAdd(&sstats[D + c0 + 3], q3);
  __syncthreads();
  atomicAdd(&stats[threadIdx.x], sstats[threadIdx.x]);
  atomicAdd(&stats[D + threadIdx.x], sstats[D + threadIdx.x]);
}

__global__ void bn_fin_kernel(const float* __restrict__ stats, const float* __restrict__ gamma,
                              const float* __restrict__ beta, float* __restrict__ scale,
                              float* __restrict__ shift) {
  int c = threadIdx.x;
  float mean = stats[c] * (1.0f / M_NODES);
  float var = stats[D + c] * (1.0f / M_NODES) - mean * mean;
  float rstd = rsqrtf(var + 1e-5f);
  float sc = gamma[c] * rstd;
  scale[c] = sc;
  shift[c] = beta[c] - mean * sc;
}

__global__ void norm_bf16_kernel(const ushort* __restrict__ AB, const float* __restrict__ scale,
                                 const float* __restrict__ shift, ushort* __restrict__ hout) {
  size_t idx = (size_t)blockIdx.x * 256 + threadIdx.x;  // M*D/8
  if (idx >= (size_t)M_NODES * D / 8) return;
  size_t i = idx >> 5; int c = (int)(idx & 31) * 8;
  uint4 u = *(const uint4*)(AB + i * D2 + D + c);
  float4 sc0 = *(const float4*)(scale + c), sc1 = *(const float4*)(scale + c + 4);
  float4 sh0 = *(const float4*)(shift + c), sh1 = *(const float4*)(shift + c + 4);
  float f0 = fmaxf(bf2f(u.x & 0xffff) * sc0.x + sh0.x, 0.f);
  float f1 = fmaxf(bf2f(u.x >> 16)    * sc0.y + sh0.y, 0.f);
  float f2 = fmaxf(bf2f(u.y & 0xffff) * sc0.z + sh0.z, 0.f);
  float f3 = fmaxf(bf2f(u.y >> 16)    * sc0.w + sh0.w, 0.f);
  float f4 = fmaxf(bf2f(u.z & 0xffff) * sc1.x + sh1.x, 0.f);
  float f5 = fmaxf(bf2f(u.z >> 16)    * sc1.y + sh1.y, 0.f);
  float f6 = fmaxf(bf2f(u.w & 0xffff) * sc1.z + sh1.z, 0.f);
  float f7 = fmaxf(bf2f(u.w >> 16)    * sc1.w + sh1.w, 0.f);
  uint4 o;
  o.x = f2bf(f0) | (f2bf(f1) << 16);
  o.y = f2bf(f2) | (f2bf(f3) << 16);
  o.z = f2bf(f4) | (f2bf(f5) << 16);
  o.w = f2bf(f6) | (f2bf(f7) << 16);
  *(uint4*)(hout + i * D + c) = o;
}

__global__ void norm_f32_out_kernel(const ushort* __restrict__ AB, const float* __restrict__ scale,
                                    const float* __restrict__ shift, float* __restrict__ out) {
  size_t idx = (size_t)blockIdx.x * 256 + threadIdx.x;  // M*D/8
  if (idx >= (size_t)M_NODES * D / 8) return;
  size_t i = idx >> 5; int c = (int)(idx & 31) * 8;
  uint4 u = *(const uint4*)(AB + i * D2 + D + c);
  float4 sc0 = *(const float4*)(scale + c), sc1 = *(const float4*)(scale + c + 4);
  float4 sh0 = *(const float4*)(shift + c), sh1 = *(const float4*)(shift + c + 4);
  float4 r0, r1;
  r0.x = fmaxf(bf2f(u.x & 0xffff) * sc0.x + sh0.x, 0.f);
  r0.y = fmaxf(bf2f(u.x >> 16)    * sc0.y + sh0.y, 0.f);
  r0.z = fmaxf(bf2f(u.y & 0xffff) * sc0.z + sh0.z, 0.f);
  r0.w = fmaxf(bf2f(u.y >> 16)    * sc0.w + sh0.w, 0.f);
  r1.x = fmaxf(bf2f(u.z & 0xffff) * sc1.x + sh1.x, 0.f);
  r1.y = fmaxf(bf2f(u.z >> 16)    * sc1.y + sh1.y, 0.f);
  r1.z = fmaxf(bf2f(u.w & 0xffff) * sc1.z + sh1.z, 0.f);
  r1.w = fmaxf(bf2f(u.w >> 16)    * sc1.w + sh1.w, 0.f);
  *(float4*)(out + i * D2 + c) = r0;
  *(float4*)(out + i * D2 + c + 4) = r1;
}

// ---------------- launch ----------------
extern "C" void kernel_launch(void* const* d_in, const int* in_sizes, int n_in,
                              void* d_out, int out_size, void* d_ws, size_t ws_size,
                              hipStream_t stream) {
  const float* x      = (const float*)d_in[0];
  const float* vals   = (const float*)d_in[1];
  const float* W      = (const float*)d_in[2];
  const float* SW     = (const float*)d_in[3];
  const float* gammas = (const float*)d_in[4];
  const float* betas  = (const float*)d_in[5];
  const int*   rows   = (const int*)d_in[6];
  const int*   cols   = (const int*)d_in[7];
  float* out = (float*)d_out;

  char* ws = (char*)d_ws;
  size_t off = 0;
  auto alloc = [&](size_t bytes) {
    void* p = ws + off;
    off = (off + bytes + 255) & ~(size_t)255;
    return p;
  };
  ushort* h    = (ushort*)alloc((size_t)M_NODES * D * 2);
  ushort* AB   = (ushort*)alloc((size_t)M_NODES * D2 * 2);
  ushort* Bt   = (ushort*)alloc((size_t)NLAYERS * D2 * D * 2);
  int*   rp    = (int*)alloc((M_NODES + 1) * 4);
  int*   cursor= (int*)alloc((M_NODES + 1) * 4);
  int*   e_col = (int*)alloc(NE * 4);
  float* e_val = (float*)alloc(NE * 4);
  int*   bsum  = (int*)alloc(512);
  int*   boff  = (int*)alloc(512);
  float* stats = (float*)alloc(NLAYERS * 2 * D * 4);
  float* scale = (float*)alloc(D * 4);
  float* shift = (float*)alloc(D * 4);

  hipMemsetAsync(cursor, 0, (size_t)M_NODES * 4, stream);  // counts
  hipMemsetAsync(stats, 0, (size_t)NLAYERS * 2 * D * 4, stream);

  hist_kernel<<<(NE + 255) / 256, 256, 0, stream>>>(rows, cursor);
  scan1_kernel<<<98, 256, 0, stream>>>(cursor, rp, bsum);
  scan2_kernel<<<1, 128, 0, stream>>>(bsum, boff);
  scan3_kernel<<<(M_NODES + 256) / 256, 256, 0, stream>>>(rp, boff, cursor);
  scatter_kernel<<<(NE + 255) / 256, 256, 0, stream>>>(rows, cols, vals, cursor, e_col, e_val);

  conv_x_kernel<<<(M_NODES * D / 4) / 256, 256, 0, stream>>>(x, h);
  conv_w_kernel<<<(NLAYERS * D2 * D) / 256, 256, 0, stream>>>(W, SW, Bt);
  copy_x_kernel<<<(M_NODES * D / 4) / 256, 256, 0, stream>>>(x, out);

  const int spmm_blocks = (M_NODES + SPMM_CHUNK * 4 - 1) / (SPMM_CHUNK * 4);
  for (int lyr = 0; lyr < NLAYERS; ++lyr) {
    gemm_kernel<<<dim3((M_NODES + BM - 1) / BM, D2 / BN), 256, 0, stream>>>(
        h, Bt + (size_t)lyr * D2 * D, AB);
    spmm_kernel<<<spmm_blocks, 256, 0, stream>>>(AB, rp, e_col, e_val,
                                                 stats + (size_t)lyr * 2 * D);
    bn_fin_kernel<<<1, 256, 0, stream>>>(stats + (size_t)lyr * 2 * D, gammas + lyr * D,
                                         betas + lyr * D, scale, shift);
    if (lyr < NLAYERS - 1)
      norm_bf16_kernel<<<(M_NODES * D / 8) / 256 + 1, 256, 0, stream>>>(AB, scale, shift, h);
    else
      norm_f32_out_kernel<<<(M_NODES * D / 8) / 256 + 1, 256, 0, stream>>>(AB, scale, shift, out);
  }
}